// Round 2
// baseline (474.241 us; speedup 1.0000x reference)
//
#include <hip/hip_runtime.h>
#include <math.h>

// Problem constants (fixed by setup_inputs)
constexpr int KV_LEN    = 4096;
constexpr int PAGE_SZ   = 16;
constexpr int SHIFT     = 16;
constexpr int BSZ       = 4;
constexpr int SEQ_LEN   = 512;
constexpr int HEADS     = 16;
constexpr int HEAD_DIM  = 128;
constexpr int PAGES     = BSZ * KV_LEN / PAGE_SZ;  // 1024
constexpr int PPS       = PAGES / BSZ;             // 256 pages per sequence
constexpr int KEEP      = KV_LEN - SHIFT;          // 4080
constexpr int CUT       = KEEP - SEQ_LEN;          // 3568
constexpr int PAGE_STR  = 2 * PAGE_SZ * HEADS * HEAD_DIM;  // 65536 floats
constexpr int C_STR     = PAGE_SZ * HEADS * HEAD_DIM;      // 32768 floats
constexpr int S_STR     = HEADS * HEAD_DIM;                // 2048 floats
// Page-granular boundaries (CUT and KEEP are multiples of PAGE_SZ):
constexpr int PP_CUT    = CUT / PAGE_SZ;                   // 223
constexpr int PP_KEEP   = KEEP / PAGE_SZ;                  // 255
constexpr int PP_SHIFT  = (SHIFT + SEQ_LEN) / PAGE_SZ;     // 33

// inv[page] = position of `page` in kv_page_indices, or -1 if absent.
__global__ void build_inv(const int* __restrict__ idx, int* __restrict__ inv, int n) {
    int t = threadIdx.x;
    if (t < n) inv[t] = -1;
    __syncthreads();
    if (t < n) inv[idx[t]] = t;
}

// One block per (page, c): copy one contiguous 128 KiB region -> 128 KiB,
// fusing RoPE on the k half. Source resolution is block-uniform, done once.
__global__ __launch_bounds__(256) void kv_shift_rope(
    const float* __restrict__ kin, const float* __restrict__ vin,
    const float* __restrict__ dc,  const int*  __restrict__ pidx,
    const int*  __restrict__ inv,  float* __restrict__ out)
{
    int blk = blockIdx.x;          // PAGES * 2
    int p   = blk >> 1;
    int c   = blk & 1;             // 0=k, 1=v
    int t   = threadIdx.x;

    float* dst = out + (size_t)p * PAGE_STR + c * C_STR;

    int pos = inv[p];              // block-uniform
    const float* src;
    int  j_base = 0;
    bool rope   = false;
    if (pos < 0) {
        src = dc + (size_t)p * PAGE_STR + c * C_STR;   // passthrough
    } else {
        int b  = pos >> 8;         // / PPS
        int pp = pos & (PPS - 1);
        j_base = pp * PAGE_SZ;
        rope   = (c == 0);
        if (pp < PP_CUT) {
            int sp_ = pidx[b * PPS + pp + PP_SHIFT];
            src = dc + (size_t)sp_ * PAGE_STR + c * C_STR;
        } else if (pp < PP_KEEP) {
            const float* base = c ? vin : kin;
            src = base + (size_t)(b * SEQ_LEN + j_base - CUT) * S_STR;
        } else {
            int sp_ = pidx[b * PPS + pp];              // retained tail page
            src = dc + (size_t)sp_ * PAGE_STR + c * C_STR;
        }
    }

    if (!rope) {
        // pure contiguous copy: 32768 floats, 1 KiB per wave-instruction
        #pragma unroll 4
        for (int it = 0; it < 32; ++it) {
            int o = it * 1024 + t * 4;
            *(float4*)(dst + o) = *(const float4*)(src + o);
        }
    } else {
        const float NL = -0.20762050593046939f;  // -log2(10000)/64
        int   fi = (t * 4) & 63;                 // freq index, fixed per thread
        float f0 = exp2f((float)(fi + 0) * NL);
        float f1 = exp2f((float)(fi + 1) * NL);
        float f2 = exp2f((float)(fi + 2) * NL);
        float f3 = exp2f((float)(fi + 3) * NL);
        // lower half (d<64): out = x*cos - y*sin ; upper: out = x*cos + y*sin
        float sg = (((t * 4) & 64) == 0) ? -1.0f : 1.0f;

        #pragma unroll 4
        for (int it = 0; it < 32; ++it) {
            int o = it * 1024 + t * 4;             // contiguous per wave
            float4 x = *(const float4*)(src + o);
            float4 y;                              // partner half via shuffle
            y.x = __shfl_xor(x.x, 16);
            y.y = __shfl_xor(x.y, 16);
            y.z = __shfl_xor(x.z, 16);
            y.w = __shfl_xor(x.w, 16);
            float fj = (float)(j_base + (o >> 11));  // token position j
            float s0, c0, s1, c1, s2, c2, s3, c3;
            sincosf(fj * f0, &s0, &c0);
            sincosf(fj * f1, &s1, &c1);
            sincosf(fj * f2, &s2, &c2);
            sincosf(fj * f3, &s3, &c3);
            float4 r;
            r.x = fmaf(x.x, c0, sg * y.x * s0);
            r.y = fmaf(x.y, c1, sg * y.y * s1);
            r.z = fmaf(x.z, c2, sg * y.z * s2);
            r.w = fmaf(x.w, c3, sg * y.w * s3);
            *(float4*)(dst + o) = r;
        }
    }
}

extern "C" void kernel_launch(void* const* d_in, const int* in_sizes, int n_in,
                              void* d_out, int out_size, void* d_ws, size_t ws_size,
                              hipStream_t stream) {
    const float* kin  = (const float*)d_in[0];
    const float* vin  = (const float*)d_in[1];
    const float* dc   = (const float*)d_in[2];
    const int*   pidx = (const int*)d_in[3];
    int pages = in_sizes[3];           // 1024

    int* inv = (int*)d_ws;             // 4 KB scratch
    build_inv<<<1, pages, 0, stream>>>(pidx, inv, pages);

    kv_shift_rope<<<PAGES * 2, 256, 0, stream>>>(kin, vin, dc, pidx, inv, (float*)d_out);
}